// Round 2
// baseline (1817.272 us; speedup 1.0000x reference)
//
#include <hip/hip_runtime.h>
#include <math.h>

#define D 120
#define DP 132          // padded LDS leading dim for 128-wide tiles
#define GNUM 2048
#define RSE 15
#define NQ 30           // D/4 float4 quads per row

__device__ __forceinline__ float sigmoidf_(float x) {
    return 1.0f / (1.0f + __expf(-x));
}
__device__ __forceinline__ float tanhf_(float x) {
    // tanh(x) = 1 - 2/(e^{2x}+1); inf-safe at both ends
    return 1.0f - 2.0f / (1.0f + __expf(2.0f * x));
}

// start[g] = first index i with seg[i] >= g (seg sorted ascending); start[G] = n
__global__ void offsets_kernel(const int* __restrict__ seg, int n, int* __restrict__ start) {
    int g = blockIdx.x * blockDim.x + threadIdx.x;
    if (g > GNUM) return;
    int lo = 0, hi = n;
    while (lo < hi) {
        int mid = (lo + hi) >> 1;
        if (seg[mid] < g) lo = mid + 1; else hi = mid;
    }
    start[g] = lo;
}

// C[M][120] = act(A[M][120]) @ W^T[120][120] (+bias) ; MODE 0: plain store.
// MODE 1: input transform tanh, epilogue highway: b=GEMM+bias, a=ahw[seg[n]],
//         z=sigmoid(a+b), out = z*b + (1-z)*a
template <int MODE>
__global__ __launch_bounds__(256)
void gemm_lin(const float* __restrict__ A, const float* __restrict__ W,
              const float* __restrict__ bias, float* __restrict__ Cout, int M,
              const float* __restrict__ ahw, const int* __restrict__ seg) {
    __shared__ float at_[D * DP];  // at_[k*DP + n], n<128 (A transposed)
    __shared__ float wt_[D * DP];  // wt_[k*DP + c], c<128 (W transposed)
    int tid = threadIdx.x;
    int tc = tid & 15, tr = tid >> 4;
    int nbase = blockIdx.x * 128;

    // stage A (transposed), float4 global reads: 15 iters/thread
    for (int idx = tid; idx < 128 * NQ; idx += 256) {
        int n = idx / NQ, q = idx - n * NQ;
        int gn = nbase + n;
        float4 v = make_float4(0.f, 0.f, 0.f, 0.f);
        if (gn < M) v = *(const float4*)&A[(size_t)gn * D + q * 4];
        if (MODE == 1) { v.x = tanhf_(v.x); v.y = tanhf_(v.y); v.z = tanhf_(v.z); v.w = tanhf_(v.w); }
        int k = q * 4;
        at_[(k + 0) * DP + n] = v.x;
        at_[(k + 1) * DP + n] = v.y;
        at_[(k + 2) * DP + n] = v.z;
        at_[(k + 3) * DP + n] = v.w;
    }
    // stage W (transposed), zero-fill cols 120..127
    for (int idx = tid; idx < 128 * NQ; idx += 256) {
        int c = idx / NQ, q = idx - c * NQ;
        float4 v = make_float4(0.f, 0.f, 0.f, 0.f);
        if (c < D) v = *(const float4*)&W[c * D + q * 4];
        int k = q * 4;
        wt_[(k + 0) * DP + c] = v.x;
        wt_[(k + 1) * DP + c] = v.y;
        wt_[(k + 2) * DP + c] = v.z;
        wt_[(k + 3) * DP + c] = v.w;
    }
    __syncthreads();

    float acc[8][8];
#pragma unroll
    for (int i = 0; i < 8; ++i)
#pragma unroll
        for (int j = 0; j < 8; ++j) acc[i][j] = 0.0f;

    int an = tr * 8;
    int c0 = tc * 4;
#pragma unroll 2
    for (int k = 0; k < D; ++k) {
        float4 a0 = *(const float4*)&at_[k * DP + an];
        float4 a1 = *(const float4*)&at_[k * DP + an + 4];
        float4 w0 = *(const float4*)&wt_[k * DP + c0];
        float4 w1 = *(const float4*)&wt_[k * DP + 64 + c0];
        float av[8] = {a0.x, a0.y, a0.z, a0.w, a1.x, a1.y, a1.z, a1.w};
        float wv[8] = {w0.x, w0.y, w0.z, w0.w, w1.x, w1.y, w1.z, w1.w};
#pragma unroll
        for (int i = 0; i < 8; ++i)
#pragma unroll
            for (int j = 0; j < 8; ++j) acc[i][j] += av[i] * wv[j];
    }

    float bv[8];
#pragma unroll
    for (int j = 0; j < 4; ++j) bv[j] = bias[c0 + j];
#pragma unroll
    for (int j = 0; j < 4; ++j) {
        int c = 64 + c0 + j;
        bv[4 + j] = (c < D) ? bias[c] : 0.0f;
    }

#pragma unroll
    for (int i = 0; i < 8; ++i) {
        int gn = nbase + an + i;
        if (gn >= M) continue;
        if (MODE == 0) {
            float4 o0 = make_float4(acc[i][0] + bv[0], acc[i][1] + bv[1],
                                    acc[i][2] + bv[2], acc[i][3] + bv[3]);
            *(float4*)&Cout[(size_t)gn * D + c0] = o0;
            if (tc < 14) {
                float4 o1 = make_float4(acc[i][4] + bv[4], acc[i][5] + bv[5],
                                        acc[i][6] + bv[6], acc[i][7] + bv[7]);
                *(float4*)&Cout[(size_t)gn * D + 64 + c0] = o1;
            }
        } else {
            int g = seg[gn];
            const float* ag = ahw + (size_t)g * D;
            float4 a4 = *(const float4*)&ag[c0];
            float aa[4] = {a4.x, a4.y, a4.z, a4.w};
            float o[4];
#pragma unroll
            for (int j = 0; j < 4; ++j) {
                float b = acc[i][j] + bv[j];
                float z = sigmoidf_(aa[j] + b);
                o[j] = z * b + (1.0f - z) * aa[j];
            }
            *(float4*)&Cout[(size_t)gn * D + c0] = make_float4(o[0], o[1], o[2], o[3]);
            if (tc < 14) {
                float4 a4b = *(const float4*)&ag[64 + c0];
                float ab[4] = {a4b.x, a4b.y, a4b.z, a4b.w};
#pragma unroll
                for (int j = 0; j < 4; ++j) {
                    float b = acc[i][4 + j] + bv[4 + j];
                    float z = sigmoidf_(ab[j] + b);
                    o[j] = z * b + (1.0f - z) * ab[j];
                }
                *(float4*)&Cout[(size_t)gn * D + 64 + c0] = make_float4(o[0], o[1], o[2], o[3]);
            }
        }
    }
}

// Per-graph: channel average of s -> SE MLP -> w[g][120]
__global__ __launch_bounds__(128)
void se_kernel(const float* __restrict__ s, const int* __restrict__ start,
               const float* __restrict__ Wse1, const float* __restrict__ Wse2,
               float* __restrict__ wout) {
    int g = blockIdx.x;
    int i0 = start[g], i1 = start[g + 1];
    int t = threadIdx.x;
    __shared__ float avg_[D];
    __shared__ float t_[RSE];
    if (t < D) {
        float sum = 0.0f;
        for (int i = i0; i < i1; ++i) sum += s[(size_t)i * D + t];
        float cnt = (float)(i1 - i0);
        avg_[t] = sum / fmaxf(cnt, 1.0f);
    }
    __syncthreads();
    if (t < RSE) {
        float a = 0.0f;
        for (int j = 0; j < D; ++j) a += avg_[j] * Wse1[t * D + j];
        t_[t] = fmaxf(a, 0.0f);
    }
    __syncthreads();
    if (t < D) {
        float a = 0.0f;
#pragma unroll
        for (int k = 0; k < RSE; ++k) a += t_[k] * Wse2[t * RSE + k];
        wout[(size_t)g * D + t] = sigmoidf_(a);
    }
}

// Per-graph: m_i = mean_c(s_i*w), A = sum s_i*m_i, B = sum sigmoid(s_i),
// pooled = A*B, then a_hw[g] = pooled @ W_hw^T + b_hw
__global__ __launch_bounds__(256)
void pool_kernel(const float* __restrict__ s, const int* __restrict__ start,
                 const float* __restrict__ wse, const float* __restrict__ Whw,
                 const float* __restrict__ bhw, float* __restrict__ ahw) {
    int g = blockIdx.x;
    int i0 = start[g], i1 = start[g + 1];
    int t = threadIdx.x;
    int lane = t & 63, wv = t >> 6;
    __shared__ float wl_[D];
    __shared__ float red_[8][D];
    __shared__ float pooled_[D];
    __shared__ float whw_[D * 121];
    if (t < D) wl_[t] = wse[(size_t)g * D + t];
    for (int idx = t; idx < D * D; idx += 256) {
        int c = idx / D, k = idx - c * D;
        whw_[c * 121 + k] = Whw[idx];
    }
    __syncthreads();
    float w0 = wl_[lane];
    float w1 = (lane < D - 64) ? wl_[lane + 64] : 0.0f;
    float A0 = 0, A1 = 0, B0 = 0, B1 = 0;
    for (int i = i0 + wv; i < i1; i += 4) {
        const float* row = s + (size_t)i * D;
        float s0 = row[lane];
        float s1 = (lane < D - 64) ? row[lane + 64] : 0.0f;
        float d = s0 * w0 + s1 * w1;
#pragma unroll
        for (int off = 32; off > 0; off >>= 1) d += __shfl_xor(d, off);
        float m = d * (1.0f / D);
        A0 += s0 * m;
        A1 += s1 * m;
        B0 += sigmoidf_(s0);
        B1 += sigmoidf_(s1);
    }
    red_[wv][lane] = A0;
    red_[4 + wv][lane] = B0;
    if (lane < D - 64) {
        red_[wv][lane + 64] = A1;
        red_[4 + wv][lane + 64] = B1;
    }
    __syncthreads();
    if (t < D) {
        float A = red_[0][t] + red_[1][t] + red_[2][t] + red_[3][t];
        float B = red_[4][t] + red_[5][t] + red_[6][t] + red_[7][t];
        pooled_[t] = A * B;
    }
    __syncthreads();
    if (t < D) {
        float acc = bhw[t];
        for (int j = 0; j < D; ++j) acc += pooled_[j] * whw_[t * 121 + j];
        ahw[(size_t)g * D + t] = acc;
    }
}

// Fused GRU: gi = vbl@w_ih^T+b_ih, gh = h@w_hh^T+b_hh (r,z via K=240 concat),
// n = tanh(i_n + r*h_n), out = (1-z)*z_h... out = (1-z)*n + z*h
__global__ __launch_bounds__(256)
void gru_kernel(const float* __restrict__ vbl, const float* __restrict__ h,
                const float* __restrict__ wih, const float* __restrict__ whh,
                const float* __restrict__ bih, const float* __restrict__ bhh,
                float* __restrict__ out, int M) {
    __shared__ float at_[240 * 68];  // at_[k*68 + n]; k<120: vbl, k>=120: h
    __shared__ float wt_[D * DP];
    int tid = threadIdx.x;
    int tc = tid & 15, tr = tid >> 4;
    int nbase = blockIdx.x * 64;

    // stage concat [vbl | h] transposed, float4 global reads: 15 iters/thread
    for (int idx = tid; idx < 64 * 60; idx += 256) {
        int n = idx / 60, q = idx - n * 60;
        int gn = nbase + n;
        int k = q * 4;
        float4 v = make_float4(0.f, 0.f, 0.f, 0.f);
        if (gn < M) {
            v = (k < D) ? *(const float4*)&vbl[(size_t)gn * D + k]
                        : *(const float4*)&h[(size_t)gn * D + (k - D)];
        }
        at_[(k + 0) * 68 + n] = v.x;
        at_[(k + 1) * 68 + n] = v.y;
        at_[(k + 2) * 68 + n] = v.z;
        at_[(k + 3) * 68 + n] = v.w;
    }

    auto stageW = [&](const float* Wp) {
        __syncthreads();
        for (int idx = tid; idx < 128 * NQ; idx += 256) {
            int c = idx / NQ, q = idx - c * NQ;
            float4 v = make_float4(0.f, 0.f, 0.f, 0.f);
            if (c < D) v = *(const float4*)&Wp[c * D + q * 4];
            int k = q * 4;
            wt_[(k + 0) * DP + c] = v.x;
            wt_[(k + 1) * DP + c] = v.y;
            wt_[(k + 2) * DP + c] = v.z;
            wt_[(k + 3) * DP + c] = v.w;
        }
        __syncthreads();
    };

    int an = tr * 4;
    int c0 = tc * 4;

    auto accpass = [&](int koff, float (&acc)[4][8]) {
#pragma unroll 2
        for (int k = 0; k < D; ++k) {
            float4 a0 = *(const float4*)&at_[(koff + k) * 68 + an];
            float4 w0 = *(const float4*)&wt_[k * DP + c0];
            float4 w1 = *(const float4*)&wt_[k * DP + 64 + c0];
            float av[4] = {a0.x, a0.y, a0.z, a0.w};
            float wv2[8] = {w0.x, w0.y, w0.z, w0.w, w1.x, w1.y, w1.z, w1.w};
#pragma unroll
            for (int i = 0; i < 4; ++i)
#pragma unroll
                for (int j = 0; j < 8; ++j) acc[i][j] += av[i] * wv2[j];
        }
    };
    auto zero = [&](float (&acc)[4][8]) {
#pragma unroll
        for (int i = 0; i < 4; ++i)
#pragma unroll
            for (int j = 0; j < 8; ++j) acc[i][j] = 0.0f;
    };

    int cch[8];
    bool cval[8];
#pragma unroll
    for (int j = 0; j < 8; ++j) {
        int c = (j < 4) ? (c0 + j) : (64 + c0 + (j - 4));
        cch[j] = c;
        cval[j] = (c < D);
    }

    float r[4][8], zz[4][8], acc[4][8];

    // ---- r gate ----
    zero(acc);
    stageW(wih);
    accpass(0, acc);
    stageW(whh);
    accpass(D, acc);
#pragma unroll
    for (int j = 0; j < 8; ++j) {
        float bsum = cval[j] ? (bih[cch[j]] + bhh[cch[j]]) : 0.0f;
#pragma unroll
        for (int i = 0; i < 4; ++i) r[i][j] = sigmoidf_(acc[i][j] + bsum);
    }

    // ---- z gate ----
    zero(acc);
    stageW(wih + D * D);
    accpass(0, acc);
    stageW(whh + D * D);
    accpass(D, acc);
#pragma unroll
    for (int j = 0; j < 8; ++j) {
        float bsum = cval[j] ? (bih[D + cch[j]] + bhh[D + cch[j]]) : 0.0f;
#pragma unroll
        for (int i = 0; i < 4; ++i) zz[i][j] = sigmoidf_(acc[i][j] + bsum);
    }

    // ---- n gate: h_n part first ----
    zero(acc);
    stageW(whh + 2 * D * D);
    accpass(D, acc);
#pragma unroll
    for (int j = 0; j < 8; ++j) {
        float bn = cval[j] ? bhh[2 * D + cch[j]] : 0.0f;
#pragma unroll
        for (int i = 0; i < 4; ++i) r[i][j] = r[i][j] * (acc[i][j] + bn);  // r <- r*h_n
    }
    zero(acc);
    stageW(wih + 2 * D * D);
    accpass(0, acc);

    // ---- combine + store ----
#pragma unroll
    for (int i = 0; i < 4; ++i) {
        int gn = nbase + an + i;
        if (gn >= M) continue;
        float o[4];
#pragma unroll
        for (int j = 0; j < 4; ++j) {
            float bn = bih[2 * D + cch[j]];
            float nv = tanhf_(acc[i][j] + bn + r[i][j]);
            float hv = at_[(D + cch[j]) * 68 + (an + i)];
            o[j] = (1.0f - zz[i][j]) * nv + zz[i][j] * hv;
        }
        *(float4*)&out[(size_t)gn * D + c0] = make_float4(o[0], o[1], o[2], o[3]);
        if (tc < 14) {
#pragma unroll
            for (int j = 0; j < 4; ++j) {
                float bn = bih[2 * D + cch[4 + j]];
                float nv = tanhf_(acc[i][4 + j] + bn + r[i][4 + j]);
                float hv = at_[(D + cch[4 + j]) * 68 + (an + i)];
                o[j] = (1.0f - zz[i][4 + j]) * nv + zz[i][4 + j] * hv;
            }
            *(float4*)&out[(size_t)gn * D + 64 + c0] = make_float4(o[0], o[1], o[2], o[3]);
        }
    }
}

extern "C" void kernel_launch(void* const* d_in, const int* in_sizes, int n_in,
                              void* d_out, int out_size, void* d_ws, size_t ws_size,
                              hipStream_t stream) {
    const float* va = (const float*)d_in[0];
    const float* vb = (const float*)d_in[1];
    const float* W_L = (const float*)d_in[2];
    const float* b_L = (const float*)d_in[3];
    const float* W_se1 = (const float*)d_in[4];
    const float* W_se2 = (const float*)d_in[5];
    const float* W_hw = (const float*)d_in[6];
    const float* b_hw = (const float*)d_in[7];
    const float* w_ih = (const float*)d_in[8];
    const float* w_hh = (const float*)d_in[9];
    const float* b_ih = (const float*)d_in[10];
    const float* b_hh = (const float*)d_in[11];
    const int* seg_a = (const int*)d_in[12];
    const int* seg_b = (const int*)d_in[13];

    int Na = in_sizes[0] / D;
    int Nb = in_sizes[1] / D;
    float* out = (float*)d_out;

    char* ws = (char*)d_ws;
    size_t offs = 0;
    auto alloc = [&](size_t bytes) -> void* {
        void* p = ws + offs;
        offs = (offs + bytes + 255) & ~(size_t)255;
        return p;
    };
    float* sbuf = (float*)alloc((size_t)Na * D * sizeof(float));  // s, later reused as h
    float* vbl  = (float*)alloc((size_t)Nb * D * sizeof(float));
    float* wse  = (float*)alloc((size_t)GNUM * D * sizeof(float));
    float* ahw  = (float*)alloc((size_t)GNUM * D * sizeof(float));
    int* start_a = (int*)alloc((GNUM + 1) * sizeof(int));
    int* start_b = (int*)alloc((GNUM + 1) * sizeof(int));
    float* hbuf = sbuf;

    int obl = (GNUM + 1 + 255) / 256;
    offsets_kernel<<<obl, 256, 0, stream>>>(seg_a, Na, start_a);
    offsets_kernel<<<obl, 256, 0, stream>>>(seg_b, Nb, start_b);

    // s = va @ W_L^T + b_L
    gemm_lin<0><<<(Na + 127) / 128, 256, 0, stream>>>(va, W_L, b_L, sbuf, Na, nullptr, nullptr);
    // SE weights per graph
    se_kernel<<<GNUM, 128, 0, stream>>>(sbuf, start_a, W_se1, W_se2, wse);
    // pooled + a_hw per graph
    pool_kernel<<<GNUM, 256, 0, stream>>>(sbuf, start_a, wse, W_hw, b_hw, ahw);
    // vb_l = vb @ W_L^T + b_L
    gemm_lin<0><<<(Nb + 127) / 128, 256, 0, stream>>>(vb, W_L, b_L, vbl, Nb, nullptr, nullptr);
    // highway: h = z*b + (1-z)*a  (writes into sbuf, which is dead now)
    gemm_lin<1><<<(Nb + 127) / 128, 256, 0, stream>>>(vbl, W_hw, b_hw, hbuf, Nb, ahw, seg_b);
    // GRU
    gru_kernel<<<(Nb + 63) / 64, 256, 0, stream>>>(vbl, hbuf, w_ih, w_hh, b_ih, b_hh, out, Nb);
}